// Round 1
// baseline (1549.310 us; speedup 1.0000x reference)
//
#include <hip/hip_runtime.h>
#include <math.h>

#define NB 2048
#define NT 512
#define ND 64
#define NS 256

// ---------------------------------------------------------------------------
// Main forward kernel: one block per sequence, 256 threads = 256 joint states.
// Scaled forward algorithm in linear space:
//   v[s] ~ normalized exp(alpha), L = accumulated log-scale.
//   step: tmp[w'][x] = sum_w Tw[w][w'] v[w][x]      (stage 1)
//         q[w'][x']  = sum_x tmp[w'][x] Tx[x][x']   (stage 2)
//         val = q * exp(logE - max logE);  L += log(sum val) + max;  v = val/sum
// ---------------------------------------------------------------------------
__global__ __launch_bounds__(256, 3) void fhmm_fwd(
    const int* __restrict__ seq, const int* __restrict__ lengths,
    const float* __restrict__ pw, const float* __restrict__ px,
    const float* __restrict__ py, float* __restrict__ partials,
    float* __restrict__ out)
{
  const int b   = blockIdx.x;
  const int tid = threadIdx.x;
  const int wp  = tid >> 4;   // w' index of this thread's output state
  const int xc  = tid & 15;   // x (stage1) / x' (stage2) index

  // Per-thread constant registers
  float Twc[16];  // Tw[w][wp]  (column wp of Tw)
  float Txc[16];  // Tx[x][xc]  (column xc of Tx)
  float W[64];    // Wemit[s][d] = log(p) - log1p(-p) for s = tid
  float base = 0.f;
#pragma unroll
  for (int w = 0; w < 16; ++w) Twc[w] = pw[w * 16 + wp];
#pragma unroll
  for (int x = 0; x < 16; ++x) Txc[x] = px[x * 16 + xc];
#pragma unroll
  for (int d = 0; d < 64; ++d) {
    float p   = py[tid * 64 + d];
    float lp  = logf(p);
    float l1p = log1pf(-p);
    W[d] = lp - l1p;
    base += l1p;
  }

  __shared__ __align__(16) float yf[64];       // y_t broadcast (uniform reads)
  __shared__ __align__(16) float v_lds[256];   // v[w][x] at w*16+x
  __shared__ __align__(16) float tmp_lds[256]; // tmp[w'][x] at w'*16+x
  __shared__ float red[8];                     // wave partials: [0..3]=max, [4..7]=sum

  const int len = lengths[b];
  const int* yb = seq + (size_t)b * (NT * ND);

  v_lds[tid] = (tid == 0) ? 1.f : 0.f;  // alpha0: deterministic state (0,0)

  float L = 0.f;
  float ynext = 0.f;
  if (tid < 64) ynext = (float)yb[tid];  // prefetch t=0

  for (int t = 0; t < len; ++t) {
    if (tid < 64) yf[tid] = ynext;
    __syncthreads();                     // B1: yf + v_lds ready
    if (tid < 64 && (t + 1) < len)       // prefetch next timestep (hides HBM latency)
      ynext = (float)yb[(t + 1) * ND + tid];

    // ---- emission logE for state tid (4 accumulators for ILP) ----
    float e0 = base, e1 = 0.f, e2 = 0.f, e3 = 0.f;
    const float4* y4p = (const float4*)yf;
#pragma unroll
    for (int i = 0; i < 16; ++i) {
      float4 y4 = y4p[i];
      e0 = fmaf(y4.x, W[4 * i + 0], e0);
      e1 = fmaf(y4.y, W[4 * i + 1], e1);
      e2 = fmaf(y4.z, W[4 * i + 2], e2);
      e3 = fmaf(y4.w, W[4 * i + 3], e3);
    }
    float e = (e0 + e1) + (e2 + e3);

    // ---- stage 1: tmp[wp][xc] = sum_w Tw[w][wp] * v[w][xc] ----
    // reads: 16 distinct addrs/wave, 16 distinct banks, 4-lane broadcast: conflict-free
    float s1a = 0.f, s1b = 0.f;
#pragma unroll
    for (int w = 0; w < 16; w += 2) {
      s1a = fmaf(Twc[w],     v_lds[w * 16 + xc],       s1a);
      s1b = fmaf(Twc[w + 1], v_lds[(w + 1) * 16 + xc], s1b);
    }
    tmp_lds[tid] = s1a + s1b;

    // ---- block max of logE (for scaling) ----
    float m = e;
#pragma unroll
    for (int off = 32; off; off >>= 1) m = fmaxf(m, __shfl_xor(m, off));
    if ((tid & 63) == 0) red[tid >> 6] = m;
    __syncthreads();                     // B2: tmp + max partials ready
    m = fmaxf(fmaxf(red[0], red[1]), fmaxf(red[2], red[3]));

    // ---- stage 2: q[wp][xc] = sum_x tmp[wp][x] * Tx[x][xc] ----
    float q0 = 0.f, q1 = 0.f;
    const float4* t4p = (const float4*)(tmp_lds + wp * 16);
#pragma unroll
    for (int i = 0; i < 4; ++i) {
      float4 t4 = t4p[i];
      q0 = fmaf(t4.x, Txc[4 * i + 0], q0);
      q1 = fmaf(t4.y, Txc[4 * i + 1], q1);
      q0 = fmaf(t4.z, Txc[4 * i + 2], q0);
      q1 = fmaf(t4.w, Txc[4 * i + 3], q1);
    }
    float val = (q0 + q1) * __expf(e - m);

    // ---- block sum + renormalize ----
    float s = val;
#pragma unroll
    for (int off = 32; off; off >>= 1) s += __shfl_xor(s, off);
    if ((tid & 63) == 0) red[4 + (tid >> 6)] = s;
    __syncthreads();                     // B3: sum partials ready
    s = (red[4] + red[5]) + (red[6] + red[7]);

    L += __logf(s) + m;
    v_lds[tid] = val * (1.0f / s);
    // no barrier needed here: B1 of next iteration orders v_lds writes vs reads
  }

  if (partials) {
    if (tid == 0) partials[b] = L;
  } else {
    if (tid == 0) atomicAdd(out, L);
  }
}

// ---------------------------------------------------------------------------
// Finalize: sum per-sequence log-likelihoods (deterministic tree) + priors.
// gammaln constants (conc = 0.9*I + 0.1, Beta(0.1, 0.9)) are compile-time:
//   gammaln(2.5)=0.2846828704729192, gammaln(0.1)=2.2527126517342055,
//   gammaln(0.9)=0.0663762397347443, gammaln(1.0)=0
// ---------------------------------------------------------------------------
__global__ void fhmm_finalize(const float* __restrict__ partials,
                              const float* __restrict__ pw,
                              const float* __restrict__ px,
                              const float* __restrict__ py,
                              float* __restrict__ out)
{
  const int tid = threadIdx.x;
  float a = 0.f;
  if (partials) {
#pragma unroll
    for (int i = 0; i < 8; ++i) a += partials[tid + 256 * i];
  }
  // Dirichlet data terms: (conc-1)=0 on diag, -0.9 off-diag
  {
    int i = tid >> 4, j = tid & 15;
    if (i != j) a += -0.9f * (logf(pw[tid]) + logf(px[tid]));
  }
  // Beta data terms over all probs_y
  for (int k = 0; k < 64; ++k) {
    float p = py[tid * 64 + k];
    a += -0.9f * logf(p) - 0.1f * log1pf(-p);
  }
  __shared__ float red[256];
  red[tid] = a;
  __syncthreads();
  for (int s = 128; s > 0; s >>= 1) {
    if (tid < s) red[tid] += red[tid + s];
    __syncthreads();
  }
  if (tid == 0) {
    const float cst =
        2.f * (16.f * 0.2846828704729192f - 240.f * 2.2527126517342055f)
        - (2.2527126517342055f + 0.0663762397347443f) * 16384.f;
    out[0] = red[0] + cst;
  }
}

extern "C" void kernel_launch(void* const* d_in, const int* in_sizes, int n_in,
                              void* d_out, int out_size, void* d_ws, size_t ws_size,
                              hipStream_t stream) {
  const int*   seq = (const int*)d_in[0];
  const int*   len = (const int*)d_in[1];
  const float* pw  = (const float*)d_in[2];
  const float* px  = (const float*)d_in[3];
  const float* py  = (const float*)d_in[4];
  float*       out = (float*)d_out;

  if (ws_size >= NB * sizeof(float)) {
    // Deterministic path: per-sequence partials in workspace, tree-reduced.
    float* partials = (float*)d_ws;
    fhmm_fwd<<<NB, 256, 0, stream>>>(seq, len, pw, px, py, partials, out);
    fhmm_finalize<<<1, 256, 0, stream>>>(partials, pw, px, py, out);
  } else {
    // Fallback: priors first (sets out), then atomic accumulation.
    fhmm_finalize<<<1, 256, 0, stream>>>(nullptr, pw, px, py, out);
    fhmm_fwd<<<NB, 256, 0, stream>>>(seq, len, pw, px, py, nullptr, out);
  }
}

// Round 2
// 573.302 us; speedup vs baseline: 2.7024x; 2.7024x over previous
//
#include <hip/hip_runtime.h>
#include <math.h>

#define NB 2048
#define NT 512
#define ND 64

typedef float f32x4 __attribute__((ext_vector_type(4)));
typedef short s16x8 __attribute__((ext_vector_type(8)));

__device__ __forceinline__ unsigned short bf16rn(float f) {
  unsigned u = __float_as_uint(f);
  unsigned r = u + 0x7FFFu + ((u >> 16) & 1u);
  return (unsigned short)(r >> 16);
}

// ---------------------------------------------------------------------------
// Init: build bf16 MFMA A-fragments of W = logit(probs_y) (16 state-tiles x
// 2 k-halves) and a base-fragment carrying sum_d log1p(-p) in k-slots 0/1
// (bf16 hi + residual lo).  Frag layout (verified m97-lineage):
//   a[i] = A[row = lane&15][k = 8*(lane>>4) + i]
// ws layout: [0,32KB) Wfrag, [32KB,48KB) base-frag, [48KB,+8KB) partials.
// ---------------------------------------------------------------------------
__global__ void fhmm_init(const float* __restrict__ py,
                          unsigned short* __restrict__ ws16)
{
  int t = blockIdx.x * 256 + threadIdx.x;
  if (t < 2048) {
    int st = t >> 7, kk = (t >> 6) & 1, l = t & 63;
    int s = st * 16 + (l & 15);
    int d0 = kk * 32 + 8 * (l >> 4);
    unsigned short* dst = ws16 + (size_t)t * 8;
#pragma unroll
    for (int i = 0; i < 8; ++i) {
      float p = py[s * 64 + d0 + i];
      dst[i] = bf16rn(logf(p) - log1pf(-p));
    }
  } else if (t < 3072) {
    int t2 = t - 2048;
    int st = t2 >> 6, l = t2 & 63;
    unsigned short v[8] = {0, 0, 0, 0, 0, 0, 0, 0};
    if (l < 16) {
      int s = st * 16 + l;
      float base = 0.f;
      for (int d = 0; d < 64; ++d) base += log1pf(-py[s * 64 + d]);
      unsigned short hi = bf16rn(base);
      float basehi = __uint_as_float(((unsigned)hi) << 16);
      v[0] = hi;
      v[1] = bf16rn(base - basehi);
    }
    unsigned short* dst = ws16 + (size_t)(2048 + t2) * 8;
#pragma unroll
    for (int i = 0; i < 8; ++i) dst[i] = v[i];
  }
}

// ---------------------------------------------------------------------------
// Main: one WAVE per sequence, 4 joint states per lane, zero barriers in the
// main loop.  Per 16-step chunk: 48 MFMAs compute E(256x16)+base; recursion
// does two 16x16 contractions in f32 (LDS broadcast reads + 4-lane shuffles),
// scaled exp, wave-sum, renormalize.
// ---------------------------------------------------------------------------
__global__ __launch_bounds__(256, 3) void fhmm_fwd2(
    const int* __restrict__ seq, const int* __restrict__ lengths,
    const float* __restrict__ pw, const float* __restrict__ px,
    const void* __restrict__ wfrag, float* __restrict__ partials)
{
  __shared__ float tx_lds[256];       // Tx row-major (block-shared)
  __shared__ float v_lds[4][256];     // per-wave v[w][x] at w*16+x
  __shared__ uint2 e_lds[4][1024];    // per-wave E chunk, bf16x4, 8B-swizzled

  const int tid = threadIdx.x;
  tx_lds[tid] = px[tid];
  __syncthreads();                    // only barrier in the kernel

  const int wv = tid >> 6, j = tid & 63;
  const int b  = blockIdx.x * 4 + wv;
  const int q  = j >> 4, tl = j & 15;        // emission-phase roles (C-layout)
  const int x0 = (j & 3) * 4, wp = j >> 2;   // recursion roles: states 4j..4j+3

  float* v_w = v_lds[wv];
  uint2* e_w = e_lds[wv];
  const s16x8* wf_g = (const s16x8*)wfrag;
  const s16x8* w2_g = wf_g + 2048;

  float Twc[16];                      // Tw column wp
#pragma unroll
  for (int w = 0; w < 16; ++w) Twc[w] = pw[w * 16 + wp];

  s16x8 f2 = {0, 0, 0, 0, 0, 0, 0, 0};   // B-frag of ones in k-rows 0,1
  if (q == 0) { f2[0] = (short)0x3F80; f2[1] = (short)0x3F80; }

  {                                   // alpha0: deterministic state (0,0)
    f32x4 vi = {0.f, 0.f, 0.f, 0.f};
    if (j == 0) vi[0] = 1.f;
    *(f32x4*)&v_w[j * 4] = vi;
  }

  const int len = lengths[b];
  const int* ybase = seq + (size_t)b * NT * ND;

  int4 ya0, ya1, yb0, yb1;            // prefetched y for current chunk
  {
    const int* yr = ybase + (size_t)tl * ND + 8 * q;
    const int4* p  = (const int4*)yr;
    const int4* p2 = (const int4*)(yr + 32);
    ya0 = p[0]; ya1 = p[1]; yb0 = p2[0]; yb1 = p2[1];
  }

  float L = 0.f;

  for (int t0 = 0; t0 < len; t0 += 16) {
    // ---- build B-frags (y as bf16 0/1) from prefetched regs ----
    union { s16x8 s; unsigned u[4]; } f0u, f1u;
    f0u.u[0] = (ya0.x ? 0x3F80u : 0u) | (ya0.y ? 0x3F800000u : 0u);
    f0u.u[1] = (ya0.z ? 0x3F80u : 0u) | (ya0.w ? 0x3F800000u : 0u);
    f0u.u[2] = (ya1.x ? 0x3F80u : 0u) | (ya1.y ? 0x3F800000u : 0u);
    f0u.u[3] = (ya1.z ? 0x3F80u : 0u) | (ya1.w ? 0x3F800000u : 0u);
    f1u.u[0] = (yb0.x ? 0x3F80u : 0u) | (yb0.y ? 0x3F800000u : 0u);
    f1u.u[1] = (yb0.z ? 0x3F80u : 0u) | (yb0.w ? 0x3F800000u : 0u);
    f1u.u[2] = (yb1.x ? 0x3F80u : 0u) | (yb1.y ? 0x3F800000u : 0u);
    f1u.u[3] = (yb1.z ? 0x3F80u : 0u) | (yb1.w ? 0x3F800000u : 0u);
    const s16x8 f0 = f0u.s, f1 = f1u.s;

    // ---- prefetch next chunk's y (hides under MFMA + recursion) ----
    if (t0 + 16 < len) {
      const int* yr = ybase + (size_t)(t0 + 16 + tl) * ND + 8 * q;
      const int4* p  = (const int4*)yr;
      const int4* p2 = (const int4*)(yr + 32);
      ya0 = p[0]; ya1 = p[1]; yb0 = p2[0]; yb1 = p2[1];
    }

    // ---- emission MFMA: E[s][tl] = base[s] + sum_d W[s][d]*y[t0+tl][d] ----
    float mloc = -3.0e38f;
#pragma unroll 4
    for (int st = 0; st < 16; ++st) {
      f32x4 acc = {0.f, 0.f, 0.f, 0.f};
      acc = __builtin_amdgcn_mfma_f32_16x16x32_bf16(w2_g[st * 64 + j], f2, acc, 0, 0, 0);
      acc = __builtin_amdgcn_mfma_f32_16x16x32_bf16(wf_g[(st * 2 + 0) * 64 + j], f0, acc, 0, 0, 0);
      acc = __builtin_amdgcn_mfma_f32_16x16x32_bf16(wf_g[(st * 2 + 1) * 64 + j], f1, acc, 0, 0, 0);
      mloc = fmaxf(mloc, fmaxf(fmaxf(acc[0], acc[1]), fmaxf(acc[2], acc[3])));
      unsigned lo = (unsigned)bf16rn(acc[0]) | ((unsigned)bf16rn(acc[1]) << 16);
      unsigned hi = (unsigned)bf16rn(acc[2]) | ((unsigned)bf16rn(acc[3]) << 16);
      int s4 = st * 4 + q;                       // (state>>2) column
      e_w[tl * 64 + (s4 ^ (tl & 7))] = make_uint2(lo, hi);
    }
    // per-timestep max over all 256 states (lanes sharing tl)
    mloc = fmaxf(mloc, __shfl_xor(mloc, 16));
    mloc = fmaxf(mloc, __shfl_xor(mloc, 32));

    // ---- recursion: nsteps sequential normalized-forward updates ----
    const int nsteps = (len - t0 < 16) ? (len - t0) : 16;
    for (int it = 0; it < nsteps; ++it) {
      const uint2 ee = e_w[it * 64 + (j ^ (it & 7))];
      const float m = __shfl(mloc, it);

      // stage 1: tmp[wp][x0..x0+3] = sum_w Tw[w][wp] * v[w][x0..x0+3]
      float t40 = 0.f, t41 = 0.f, t42 = 0.f, t43 = 0.f;
#pragma unroll
      for (int w = 0; w < 16; ++w) {
        const f32x4 vv = *(const f32x4*)&v_w[w * 16 + x0];
        t40 = fmaf(Twc[w], vv[0], t40);
        t41 = fmaf(Twc[w], vv[1], t41);
        t42 = fmaf(Twc[w], vv[2], t42);
        t43 = fmaf(Twc[w], vv[3], t43);
      }
      // gather full tmp row (16 x-values) from the 4-lane w'-group
      float tqA[4] = {t40, t41, t42, t43};
      float tqB[4], tqC[4], tqD[4];
#pragma unroll
      for (int i = 0; i < 4; ++i) {
        tqB[i] = __shfl_xor(tqA[i], 1);
        tqC[i] = __shfl_xor(tqA[i], 2);
        tqD[i] = __shfl_xor(tqA[i], 3);
      }
      // stage 2: a[x'] = sum_x tmp[wp][x] * Tx[x][x']
      float a0 = 0.f, a1 = 0.f, a2 = 0.f, a3 = 0.f;
#define S2BLK(TQ, K)                                                       \
      {                                                                    \
        const int mb = (((j & 3) ^ (K)) * 4);                              \
        _Pragma("unroll")                                                  \
        for (int i = 0; i < 4; ++i) {                                      \
          const f32x4 tx4 = *(const f32x4*)&tx_lds[(mb + i) * 16 + x0];    \
          a0 = fmaf(TQ[i], tx4[0], a0);                                    \
          a1 = fmaf(TQ[i], tx4[1], a1);                                    \
          a2 = fmaf(TQ[i], tx4[2], a2);                                    \
          a3 = fmaf(TQ[i], tx4[3], a3);                                    \
        }                                                                  \
      }
      S2BLK(tqA, 0) S2BLK(tqB, 1) S2BLK(tqC, 2) S2BLK(tqD, 3)
#undef S2BLK

      // emission + scale
      const float e0 = __uint_as_float(ee.x << 16);
      const float e1 = __uint_as_float(ee.x & 0xFFFF0000u);
      const float e2 = __uint_as_float(ee.y << 16);
      const float e3 = __uint_as_float(ee.y & 0xFFFF0000u);
      const float p0 = a0 * __expf(e0 - m);
      const float p1 = a1 * __expf(e1 - m);
      const float p2 = a2 * __expf(e2 - m);
      const float p3 = a3 * __expf(e3 - m);
      float s = (p0 + p1) + (p2 + p3);
#pragma unroll
      for (int off = 1; off < 64; off <<= 1) s += __shfl_xor(s, off);
      L += __logf(s) + m;
      const float inv = __fdividef(1.f, s);
      f32x4 vn; vn[0] = p0 * inv; vn[1] = p1 * inv; vn[2] = p2 * inv; vn[3] = p3 * inv;
      *(f32x4*)&v_w[j * 4] = vn;
    }
  }
  if (j == 0) partials[b] = L;
}

// ---------------------------------------------------------------------------
// Round-1 fallback forward kernel (block per sequence) — kept for small ws.
// ---------------------------------------------------------------------------
__global__ __launch_bounds__(256, 3) void fhmm_fwd1(
    const int* __restrict__ seq, const int* __restrict__ lengths,
    const float* __restrict__ pw, const float* __restrict__ px,
    const float* __restrict__ py, float* __restrict__ partials,
    float* __restrict__ out)
{
  const int b = blockIdx.x, tid = threadIdx.x;
  const int wp = tid >> 4, xc = tid & 15;
  float Twc[16], Txc[16], W[64], base = 0.f;
#pragma unroll
  for (int w = 0; w < 16; ++w) Twc[w] = pw[w * 16 + wp];
#pragma unroll
  for (int x = 0; x < 16; ++x) Txc[x] = px[x * 16 + xc];
#pragma unroll
  for (int d = 0; d < 64; ++d) {
    float p = py[tid * 64 + d];
    W[d] = logf(p) - log1pf(-p);
    base += log1pf(-p);
  }
  __shared__ __align__(16) float yf[64];
  __shared__ __align__(16) float v_s[256];
  __shared__ __align__(16) float tmp_s[256];
  __shared__ float red[8];
  const int len = lengths[b];
  const int* yb = seq + (size_t)b * (NT * ND);
  v_s[tid] = (tid == 0) ? 1.f : 0.f;
  float L = 0.f, ynext = 0.f;
  if (tid < 64) ynext = (float)yb[tid];
  for (int t = 0; t < len; ++t) {
    if (tid < 64) yf[tid] = ynext;
    __syncthreads();
    if (tid < 64 && (t + 1) < len) ynext = (float)yb[(t + 1) * ND + tid];
    float e0 = base, e1 = 0.f, e2 = 0.f, e3 = 0.f;
    const float4* y4p = (const float4*)yf;
#pragma unroll
    for (int i = 0; i < 16; ++i) {
      float4 y4 = y4p[i];
      e0 = fmaf(y4.x, W[4 * i + 0], e0); e1 = fmaf(y4.y, W[4 * i + 1], e1);
      e2 = fmaf(y4.z, W[4 * i + 2], e2); e3 = fmaf(y4.w, W[4 * i + 3], e3);
    }
    float e = (e0 + e1) + (e2 + e3);
    float s1a = 0.f, s1b = 0.f;
#pragma unroll
    for (int w = 0; w < 16; w += 2) {
      s1a = fmaf(Twc[w], v_s[w * 16 + xc], s1a);
      s1b = fmaf(Twc[w + 1], v_s[(w + 1) * 16 + xc], s1b);
    }
    tmp_s[tid] = s1a + s1b;
    float mm = e;
#pragma unroll
    for (int off = 32; off; off >>= 1) mm = fmaxf(mm, __shfl_xor(mm, off));
    if ((tid & 63) == 0) red[tid >> 6] = mm;
    __syncthreads();
    mm = fmaxf(fmaxf(red[0], red[1]), fmaxf(red[2], red[3]));
    float q0 = 0.f, q1 = 0.f;
    const float4* t4p = (const float4*)(tmp_s + wp * 16);
#pragma unroll
    for (int i = 0; i < 4; ++i) {
      float4 t4 = t4p[i];
      q0 = fmaf(t4.x, Txc[4 * i + 0], q0); q1 = fmaf(t4.y, Txc[4 * i + 1], q1);
      q0 = fmaf(t4.z, Txc[4 * i + 2], q0); q1 = fmaf(t4.w, Txc[4 * i + 3], q1);
    }
    float val = (q0 + q1) * __expf(e - mm);
    float s = val;
#pragma unroll
    for (int off = 32; off; off >>= 1) s += __shfl_xor(s, off);
    if ((tid & 63) == 0) red[4 + (tid >> 6)] = s;
    __syncthreads();
    s = (red[4] + red[5]) + (red[6] + red[7]);
    L += __logf(s) + mm;
    v_s[tid] = val * (1.0f / s);
  }
  if (partials) { if (tid == 0) partials[b] = L; }
  else { if (tid == 0) atomicAdd(out, L); }
}

// ---------------------------------------------------------------------------
// Finalize: deterministic tree-sum of per-sequence LLs + priors.
// ---------------------------------------------------------------------------
__global__ void fhmm_finalize(const float* __restrict__ partials,
                              const float* __restrict__ pw,
                              const float* __restrict__ px,
                              const float* __restrict__ py,
                              float* __restrict__ out)
{
  const int tid = threadIdx.x;
  float a = 0.f;
  if (partials) {
#pragma unroll
    for (int i = 0; i < 8; ++i) a += partials[tid + 256 * i];
  }
  {
    int i = tid >> 4, j = tid & 15;
    if (i != j) a += -0.9f * (logf(pw[tid]) + logf(px[tid]));
  }
  for (int k = 0; k < 64; ++k) {
    float p = py[tid * 64 + k];
    a += -0.9f * logf(p) - 0.1f * log1pf(-p);
  }
  __shared__ float red[256];
  red[tid] = a;
  __syncthreads();
  for (int s = 128; s > 0; s >>= 1) {
    if (tid < s) red[tid] += red[tid + s];
    __syncthreads();
  }
  if (tid == 0) {
    const float cst =
        2.f * (16.f * 0.2846828704729192f - 240.f * 2.2527126517342055f)
        - (2.2527126517342055f + 0.0663762397347443f) * 16384.f;
    out[0] = red[0] + cst;
  }
}

extern "C" void kernel_launch(void* const* d_in, const int* in_sizes, int n_in,
                              void* d_out, int out_size, void* d_ws, size_t ws_size,
                              hipStream_t stream) {
  const int*   seq = (const int*)d_in[0];
  const int*   len = (const int*)d_in[1];
  const float* pw  = (const float*)d_in[2];
  const float* px  = (const float*)d_in[3];
  const float* py  = (const float*)d_in[4];
  float*       out = (float*)d_out;

  const size_t NEED = 32768 + 16384 + 2048 * sizeof(float);  // 57344
  if (ws_size >= NEED) {
    unsigned short* wf = (unsigned short*)d_ws;
    float* partials = (float*)((char*)d_ws + 49152);
    fhmm_init<<<12, 256, 0, stream>>>(py, wf);
    fhmm_fwd2<<<512, 256, 0, stream>>>(seq, len, pw, px, (const void*)wf, partials);
    fhmm_finalize<<<1, 256, 0, stream>>>(partials, pw, px, py, out);
  } else if (ws_size >= 2048 * sizeof(float)) {
    float* partials = (float*)d_ws;
    fhmm_fwd1<<<NB, 256, 0, stream>>>(seq, len, pw, px, py, partials, out);
    fhmm_finalize<<<1, 256, 0, stream>>>(partials, pw, px, py, out);
  } else {
    fhmm_finalize<<<1, 256, 0, stream>>>(nullptr, pw, px, py, out);
    fhmm_fwd1<<<NB, 256, 0, stream>>>(seq, len, pw, px, py, nullptr, out);
  }
}

// Round 6
// 501.963 us; speedup vs baseline: 3.0865x; 1.1421x over previous
//
#include <hip/hip_runtime.h>
#include <math.h>

#define NB 2048
#define NT 512
#define ND 64

typedef float    f32x4 __attribute__((ext_vector_type(4)));
typedef short    s16x8 __attribute__((ext_vector_type(8)));

#define MFMA32(A,B,C) __builtin_amdgcn_mfma_f32_16x16x32_bf16((A),(B),(C),0,0,0)

#if __has_builtin(__builtin_amdgcn_exp2f)
#define EXP2F(x) __builtin_amdgcn_exp2f(x)
#else
#define EXP2F(x) __expf((x) * 0.6931471805599453f)
#endif
#if __has_builtin(__builtin_amdgcn_logf)
#define LOG2F(x) __builtin_amdgcn_logf(x)
#else
#define LOG2F(x) (__logf(x) * 1.4426950408889634f)
#endif

// Pure-C bf16 round-to-nearest-even (R1/R2-validated; compiler-visible so all
// MFMA-result hazards are modeled -- NO inline asm touches MFMA outputs).
__device__ __forceinline__ unsigned short bf16rn(float f) {
  unsigned u = __float_as_uint(f);
  unsigned r = u + 0x7FFFu + ((u >> 16) & 1u);
  return (unsigned short)(r >> 16);
}
__device__ __forceinline__ unsigned pack2(float a, float b) {
  return (unsigned)bf16rn(a) | ((unsigned)bf16rn(b) << 16);
}

union frag8 { s16x8 s8; unsigned u[4]; };

// pack D-layout f32x4 into a zero-padded MFMA32 A-frag:
// a[i<4] = bf16(x[i]) at k = 8*(lane>>4)+i ; a[4..7] = 0.
__device__ __forceinline__ s16x8 pack8(f32x4 x) {
  frag8 r;
  r.u[0] = pack2(x[0], x[1]);
  r.u[1] = pack2(x[2], x[3]);
  r.u[2] = 0u; r.u[3] = 0u;
  return r.s8;
}

// Cross-lane via HW-verified __shfl primitives only.
__device__ __forceinline__ float wave_sum64(float x) {
#pragma unroll
  for (int off = 1; off < 64; off <<= 1) x += __shfl_xor(x, off);
  return x;
}
__device__ __forceinline__ float cross_max1632(float x) {
  x = fmaxf(x, __shfl_xor(x, 16));
  x = fmaxf(x, __shfl_xor(x, 32));
  return x;
}

// ---------------------------------------------------------------------------
// Init: bf16 A-frags of W2 = logit(probs_y)*log2(e), rows PERMUTED so the
// recursion's per-lane E gather is one contiguous b64:
//   rho (emission row) -> state s = (4*(rho>>6)+(rho&3))*16 + ((rho>>2)&15)
// Base frags (sum_d log1p(-p)*log2e) as bf16 hi+lo in k-slots 0/1.
// Also ZEROES partials (so unwritten entries can never be garbage).
// ws: [0,32K) W frags, [32K,48K) base frags, [48K,56K) partials, [56K,64K) perm
// ---------------------------------------------------------------------------
__global__ void fhmm_init(const float* __restrict__ py,
                          unsigned short* __restrict__ ws16,
                          float* __restrict__ partials)
{
  const float LOG2E = 1.4426950408889634f;
  int t = blockIdx.x * 256 + threadIdx.x;
  if (t < 2048) partials[t] = 0.f;
  if (t < 2048) {
    int st = t >> 7, kk = (t >> 6) & 1, l = t & 63;
    int rho = st * 16 + (l & 15);
    int s = (4 * (rho >> 6) + (rho & 3)) * 16 + ((rho >> 2) & 15);
    int d0 = kk * 32 + 8 * (l >> 4);
    unsigned short* dst = ws16 + (size_t)t * 8;
#pragma unroll
    for (int i = 0; i < 8; ++i) {
      float p = py[s * 64 + d0 + i];
      dst[i] = bf16rn((logf(p) - log1pf(-p)) * LOG2E);
    }
  } else if (t < 3072) {
    int t2 = t - 2048;
    int st = t2 >> 6, l = t2 & 63;
    unsigned short v[8] = {0, 0, 0, 0, 0, 0, 0, 0};
    if (l < 16) {
      int rho = st * 16 + l;
      int s = (4 * (rho >> 6) + (rho & 3)) * 16 + ((rho >> 2) & 15);
      float base = 0.f;
      for (int d = 0; d < 64; ++d) base += log1pf(-py[s * 64 + d]);
      base *= LOG2E;
      unsigned short hi = bf16rn(base);
      float basehi = __uint_as_float(((unsigned)hi) << 16);
      v[0] = hi;
      v[1] = bf16rn(base - basehi);
    }
    unsigned short* dst = ws16 + (size_t)(2048 + t2) * 8;
#pragma unroll
    for (int i = 0; i < 8; ++i) dst[i] = v[i];
  }
}

// ---------------------------------------------------------------------------
// Stable counting sort of sequence indices by DESCENDING length (LPT balance).
// ---------------------------------------------------------------------------
__global__ void fhmm_sort(const int* __restrict__ lengths, int* __restrict__ perm)
{
  __shared__ int hist[513];
  __shared__ short slen[2048];
  const int tid = threadIdx.x;
  for (int i = tid; i < 512; i += 256) hist[i] = 0;
  for (int i = tid; i < 2048; i += 256) slen[i] = (short)lengths[i];
  __syncthreads();
  for (int i = tid; i < 2048; i += 256) atomicAdd(&hist[512 - (int)slen[i]], 1);
  __syncthreads();
  if (tid == 0) {
    int run = 0;
    for (int b2 = 0; b2 < 512; ++b2) { int c = hist[b2]; hist[b2] = run; run += c; }
  }
  __syncthreads();
  const int b0 = 2 * tid, b1 = 2 * tid + 1;
  int o0 = hist[b0], o1 = hist[b1];
  for (int i = 0; i < 2048; ++i) {
    int bin = 512 - (int)slen[i];
    if (bin == b0) perm[o0++] = i;
    else if (bin == b1) perm[o1++] = i;
  }
}

// ---------------------------------------------------------------------------
// Main: one wave per sequence; recursion fully in registers via the MFMA
// free-transpose chain (mfma_f32_16x16x32_bf16, K zero-padded). Per 16-step
// chunk: 48 MFMAs -> bf16 E in wave-private LDS (XOR swizzle); per step:
// 2 MFMA transitions + exp2 emission + __shfl_xor wave-sum, normalization
// deferred one step via lam = log2(s). All bf16 packing is pure C (bf16rn).
// ---------------------------------------------------------------------------
__global__ __launch_bounds__(256, 2) void fhmm_fwd2(
    const int* __restrict__ seq, const int* __restrict__ lengths,
    const float* __restrict__ pw, const float* __restrict__ px,
    const void* __restrict__ wfrag, const int* __restrict__ perm,
    float* __restrict__ partials)
{
  __shared__ uint2 e_lds[4][1024];   // 8KB per wave, wave-private (no barriers)

  const int tid = threadIdx.x;
  const int wv = tid >> 6, j = tid & 63;
  const int q = j >> 4, tl = j & 15;
  const int b = perm[(blockIdx.x << 2) | wv];
  if (b < 0 || b >= NB) return;      // guard vs. any perm corruption
  uint2* e_w = e_lds[wv];
  const s16x8* wf_g = (const s16x8*)wfrag;
  const s16x8* w2_g = wf_g + 2048;

  // Tw/Tx zero-padded B-frags: b[i<4] = T[4q+i][tl], b[4..7] = 0  (pure C)
  s16x8 twb8, txb8;
  {
    frag8 a, c;
    a.u[0] = pack2(pw[(4 * q + 0) * 16 + tl], pw[(4 * q + 1) * 16 + tl]);
    a.u[1] = pack2(pw[(4 * q + 2) * 16 + tl], pw[(4 * q + 3) * 16 + tl]);
    a.u[2] = 0u; a.u[3] = 0u;
    c.u[0] = pack2(px[(4 * q + 0) * 16 + tl], px[(4 * q + 1) * 16 + tl]);
    c.u[1] = pack2(px[(4 * q + 2) * 16 + tl], px[(4 * q + 3) * 16 + tl]);
    c.u[2] = 0u; c.u[3] = 0u;
    twb8 = a.s8; txb8 = c.s8;
  }

  s16x8 f2 = {0, 0, 0, 0, 0, 0, 0, 0};   // ones in k-rows 0,1 (base column)
  if (q == 0) { f2[0] = (short)0x3F80; f2[1] = (short)0x3F80; }

  f32x4 p = {0.f, 0.f, 0.f, 0.f};        // V in D-layout; alpha0 = delta(0,0)
  if (j == 0) p[0] = 1.f;

  const int len = lengths[b];
  const int* ybase = seq + (size_t)b * NT * ND;

  int4 ya0, ya1, yb0, yb1;
  {
    const int* yr = ybase + (size_t)tl * ND + 8 * q;
    const int4* pp  = (const int4*)yr;
    const int4* pp2 = (const int4*)(yr + 32);
    ya0 = pp[0]; ya1 = pp[1]; yb0 = pp2[0]; yb1 = pp2[1];
  }

  float L2 = 0.f, lam = 0.f;
  const f32x4 z4 = {0.f, 0.f, 0.f, 0.f};

  for (int t0 = 0; t0 < len; t0 += 16) {
    union { s16x8 s; unsigned u[4]; } f0u, f1u;
    f0u.u[0] = (ya0.x ? 0x3F80u : 0u) | (ya0.y ? 0x3F800000u : 0u);
    f0u.u[1] = (ya0.z ? 0x3F80u : 0u) | (ya0.w ? 0x3F800000u : 0u);
    f0u.u[2] = (ya1.x ? 0x3F80u : 0u) | (ya1.y ? 0x3F800000u : 0u);
    f0u.u[3] = (ya1.z ? 0x3F80u : 0u) | (ya1.w ? 0x3F800000u : 0u);
    f1u.u[0] = (yb0.x ? 0x3F80u : 0u) | (yb0.y ? 0x3F800000u : 0u);
    f1u.u[1] = (yb0.z ? 0x3F80u : 0u) | (yb0.w ? 0x3F800000u : 0u);
    f1u.u[2] = (yb1.x ? 0x3F80u : 0u) | (yb1.y ? 0x3F800000u : 0u);
    f1u.u[3] = (yb1.z ? 0x3F80u : 0u) | (yb1.w ? 0x3F800000u : 0u);
    const s16x8 f0 = f0u.s, f1 = f1u.s;

    if (t0 + 16 < len) {   // prefetch next chunk's y under compute
      const int* yr = ybase + (size_t)(t0 + 16 + tl) * ND + 8 * q;
      const int4* pp  = (const int4*)yr;
      const int4* pp2 = (const int4*)(yr + 32);
      ya0 = pp[0]; ya1 = pp[1]; yb0 = pp2[0]; yb1 = pp2[1];
    }

    // ---- emission: E_perm[rho][tl] (log2 units, incl base), bf16 to LDS ----
    float mloc = -3.0e38f;
#pragma unroll
    for (int st = 0; st < 16; ++st) {
      f32x4 acc = MFMA32(w2_g[st * 64 + j], f2, z4);
      acc = MFMA32(wf_g[(2 * st + 0) * 64 + j], f0, acc);
      acc = MFMA32(wf_g[(2 * st + 1) * 64 + j], f1, acc);
      mloc = fmaxf(mloc, fmaxf(fmaxf(acc[0], acc[1]), fmaxf(acc[2], acc[3])));
      unsigned lo = pack2(acc[0], acc[1]);
      unsigned hi = pack2(acc[2], acc[3]);
      e_w[tl * 64 + ((st * 4 + q) ^ tl)] = make_uint2(lo, hi);
    }
    mloc = cross_max1632(mloc);   // lane tl now holds m_t for timestep t0+tl

    // ---- recursion: register-only MFMA chain, 1x ds_read_b64 per step ----
    const int nsteps = (len - t0 < 16) ? (len - t0) : 16;
    uint2 ev = e_w[j];            // it=0 slot
    for (int it = 0; it < nsteps; ++it) {
      const uint2 ec = ev;
      const int itn = (it + 1) & 15;
      ev = e_w[itn * 64 + (j ^ itn)];          // prefetch next step
      const float mm = __shfl(mloc, it) + lam;
      f32x4 P = MFMA32(pack8(p), twb8, z4);    // P = V^T * Tw  (D->A transpose)
      f32x4 U = MFMA32(pack8(P), txb8, z4);    // U = Tw^T V Tx (w-major)
      const float e0 = __uint_as_float(ec.x << 16);
      const float e1 = __uint_as_float(ec.x & 0xFFFF0000u);
      const float e2 = __uint_as_float(ec.y << 16);
      const float e3 = __uint_as_float(ec.y & 0xFFFF0000u);
      f32x4 pn;
      pn[0] = U[0] * EXP2F(fminf(e0 - mm, 40.0f));  // 40 > legit max (-lam~20)
      pn[1] = U[1] * EXP2F(fminf(e1 - mm, 40.0f));  // inert when correct,
      pn[2] = U[2] * EXP2F(fminf(e2 - mm, 40.0f));  // blocks Inf when not
      pn[3] = U[3] * EXP2F(fminf(e3 - mm, 40.0f));
      float s = (pn[0] + pn[1]) + (pn[2] + pn[3]);
      s = wave_sum64(s);                       // __shfl_xor reduce (verified)
      s = fmaxf(s, 1e-35f);                    // guard: log can never NaN
      lam = LOG2F(s);
      L2 += mm;
      p = pn;
    }
  }
  L2 += lam;                                    // final log2(s_T)
  if (j == 0) partials[b] = L2 * 0.6931471805599453f;
}

// ---------------------------------------------------------------------------
// Round-1 fallback (block per sequence) for small workspace.
// ---------------------------------------------------------------------------
__global__ __launch_bounds__(256, 3) void fhmm_fwd1(
    const int* __restrict__ seq, const int* __restrict__ lengths,
    const float* __restrict__ pw, const float* __restrict__ px,
    const float* __restrict__ py, float* __restrict__ partials,
    float* __restrict__ out)
{
  const int b = blockIdx.x, tid = threadIdx.x;
  const int wp = tid >> 4, xc = tid & 15;
  float Twc[16], Txc[16], W[64], base = 0.f;
#pragma unroll
  for (int w = 0; w < 16; ++w) Twc[w] = pw[w * 16 + wp];
#pragma unroll
  for (int x = 0; x < 16; ++x) Txc[x] = px[x * 16 + xc];
#pragma unroll
  for (int d = 0; d < 64; ++d) {
    float pv = py[tid * 64 + d];
    W[d] = logf(pv) - log1pf(-pv);
    base += log1pf(-pv);
  }
  __shared__ __align__(16) float yf[64];
  __shared__ __align__(16) float v_s[256];
  __shared__ __align__(16) float tmp_s[256];
  __shared__ float red[8];
  const int len = lengths[b];
  const int* yb = seq + (size_t)b * (NT * ND);
  v_s[tid] = (tid == 0) ? 1.f : 0.f;
  float L = 0.f, ynext = 0.f;
  if (tid < 64) ynext = (float)yb[tid];
  for (int t = 0; t < len; ++t) {
    if (tid < 64) yf[tid] = ynext;
    __syncthreads();
    if (tid < 64 && (t + 1) < len) ynext = (float)yb[(t + 1) * ND + tid];
    float e0 = base, e1 = 0.f, e2 = 0.f, e3 = 0.f;
    const float4* y4p = (const float4*)yf;
#pragma unroll
    for (int i = 0; i < 16; ++i) {
      float4 y4 = y4p[i];
      e0 = fmaf(y4.x, W[4 * i + 0], e0); e1 = fmaf(y4.y, W[4 * i + 1], e1);
      e2 = fmaf(y4.z, W[4 * i + 2], e2); e3 = fmaf(y4.w, W[4 * i + 3], e3);
    }
    float e = (e0 + e1) + (e2 + e3);
    float s1a = 0.f, s1b = 0.f;
#pragma unroll
    for (int w = 0; w < 16; w += 2) {
      s1a = fmaf(Twc[w], v_s[w * 16 + xc], s1a);
      s1b = fmaf(Twc[w + 1], v_s[(w + 1) * 16 + xc], s1b);
    }
    tmp_s[tid] = s1a + s1b;
    float mm = e;
#pragma unroll
    for (int off = 32; off; off >>= 1) mm = fmaxf(mm, __shfl_xor(mm, off));
    if ((tid & 63) == 0) red[tid >> 6] = mm;
    __syncthreads();
    mm = fmaxf(fmaxf(red[0], red[1]), fmaxf(red[2], red[3]));
    float q0 = 0.f, q1 = 0.f;
    const float4* t4p = (const float4*)(tmp_s + wp * 16);
#pragma unroll
    for (int i = 0; i < 4; ++i) {
      float4 t4 = t4p[i];
      q0 = fmaf(t4.x, Txc[4 * i + 0], q0); q1 = fmaf(t4.y, Txc[4 * i + 1], q1);
      q0 = fmaf(t4.z, Txc[4 * i + 2], q0); q1 = fmaf(t4.w, Txc[4 * i + 3], q1);
    }
    float val = (q0 + q1) * __expf(e - mm);
    float s = val;
#pragma unroll
    for (int off = 32; off; off >>= 1) s += __shfl_xor(s, off);
    if ((tid & 63) == 0) red[4 + (tid >> 6)] = s;
    __syncthreads();
    s = (red[4] + red[5]) + (red[6] + red[7]);
    L += __logf(s) + mm;
    v_s[tid] = val * (1.0f / s);
  }
  if (partials) { if (tid == 0) partials[b] = L; }
  else { if (tid == 0) atomicAdd(out, L); }
}

// ---------------------------------------------------------------------------
// Finalize: deterministic tree-sum of per-sequence LLs + priors.
// ---------------------------------------------------------------------------
__global__ void fhmm_finalize(const float* __restrict__ partials,
                              const float* __restrict__ pw,
                              const float* __restrict__ px,
                              const float* __restrict__ py,
                              float* __restrict__ out)
{
  const int tid = threadIdx.x;
  float a = 0.f;
  if (partials) {
#pragma unroll
    for (int i = 0; i < 8; ++i) a += partials[tid + 256 * i];
  }
  {
    int i = tid >> 4, j = tid & 15;
    if (i != j) a += -0.9f * (logf(pw[tid]) + logf(px[tid]));
  }
  for (int k = 0; k < 64; ++k) {
    float p = py[tid * 64 + k];
    a += -0.9f * logf(p) - 0.1f * log1pf(-p);
  }
  __shared__ float red[256];
  red[tid] = a;
  __syncthreads();
  for (int s = 128; s > 0; s >>= 1) {
    if (tid < s) red[tid] += red[tid + s];
    __syncthreads();
  }
  if (tid == 0) {
    const float cst =
        2.f * (16.f * 0.2846828704729192f - 240.f * 2.2527126517342055f)
        - (2.2527126517342055f + 0.0663762397347443f) * 16384.f;
    out[0] = red[0] + cst;
  }
}

extern "C" void kernel_launch(void* const* d_in, const int* in_sizes, int n_in,
                              void* d_out, int out_size, void* d_ws, size_t ws_size,
                              hipStream_t stream) {
  const int*   seq = (const int*)d_in[0];
  const int*   len = (const int*)d_in[1];
  const float* pw  = (const float*)d_in[2];
  const float* px  = (const float*)d_in[3];
  const float* py  = (const float*)d_in[4];
  float*       out = (float*)d_out;

  const size_t NEED = 65536;  // 32K wfrag + 16K base + 8K partials + 8K perm
  if (ws_size >= NEED) {
    unsigned short* wf = (unsigned short*)d_ws;
    float* partials = (float*)((char*)d_ws + 49152);
    int*   perm     = (int*)((char*)d_ws + 57344);
    fhmm_init<<<12, 256, 0, stream>>>(py, wf, partials);
    fhmm_sort<<<1, 256, 0, stream>>>(len, perm);
    fhmm_fwd2<<<512, 256, 0, stream>>>(seq, len, pw, px, (const void*)wf, perm, partials);
    fhmm_finalize<<<1, 256, 0, stream>>>(partials, pw, px, py, out);
  } else if (ws_size >= 2048 * sizeof(float)) {
    float* partials = (float*)d_ws;
    fhmm_fwd1<<<NB, 256, 0, stream>>>(seq, len, pw, px, py, partials, out);
    fhmm_finalize<<<1, 256, 0, stream>>>(partials, pw, px, py, out);
  } else {
    fhmm_finalize<<<1, 256, 0, stream>>>(nullptr, pw, px, py, out);
    fhmm_fwd1<<<NB, 256, 0, stream>>>(seq, len, pw, px, py, nullptr, out);
  }
}

// Round 7
// 260.739 us; speedup vs baseline: 5.9420x; 1.9252x over previous
//
#include <hip/hip_runtime.h>
#include <math.h>

#define NB 2048
#define NT 512
#define ND 64

typedef float    f32x4 __attribute__((ext_vector_type(4)));
typedef short    s16x8 __attribute__((ext_vector_type(8)));

#define MFMA32(A,B,C) __builtin_amdgcn_mfma_f32_16x16x32_bf16((A),(B),(C),0,0,0)

#if __has_builtin(__builtin_amdgcn_exp2f)
#define EXP2F(x) __builtin_amdgcn_exp2f(x)
#else
#define EXP2F(x) __expf((x) * 0.6931471805599453f)
#endif
#if __has_builtin(__builtin_amdgcn_logf)
#define LOG2F(x) __builtin_amdgcn_logf(x)
#else
#define LOG2F(x) (__logf(x) * 1.4426950408889634f)
#endif
#if __has_builtin(__builtin_amdgcn_rcpf)
#define RCPF(x) __builtin_amdgcn_rcpf(x)
#else
#define RCPF(x) __fdividef(1.0f, (x))
#endif

// Pure-C bf16 round-to-nearest-even (validated R1/R2/R6) -- init-time & E path.
__device__ __forceinline__ unsigned short bf16rn(float f) {
  unsigned u = __float_as_uint(f);
  unsigned r = u + 0x7FFFu + ((u >> 16) & 1u);
  return (unsigned short)(r >> 16);
}
__device__ __forceinline__ unsigned pack2(float a, float b) {
  return (unsigned)bf16rn(a) | ((unsigned)bf16rn(b) << 16);
}
// Truncating bf16 pack (hot loop): 3 ops. Uniform-scale bias cancels through
// the normalization accounting; residual noise <=0.4% relative per step.
__device__ __forceinline__ unsigned pack2t(float a, float b) {
  return (__float_as_uint(a) >> 16) | (__float_as_uint(b) & 0xFFFF0000u);
}

union frag8 { s16x8 s8; unsigned u[4]; };

// pack D-layout f32x4 into a zero-padded MFMA32 A-frag (k = 8*(lane>>4)+i).
__device__ __forceinline__ s16x8 pack8t(f32x4 x) {
  frag8 r;
  r.u[0] = pack2t(x[0], x[1]);
  r.u[1] = pack2t(x[2], x[3]);
  r.u[2] = 0u; r.u[3] = 0u;
  return r.s8;
}

__device__ __forceinline__ float cross_max1632(float x) {
  x = fmaxf(x, __shfl_xor(x, 16));
  x = fmaxf(x, __shfl_xor(x, 32));
  return x;
}

// ---------------------------------------------------------------------------
// Init: bf16 A-frags of W2 = logit(probs_y)*log2(e), rows PERMUTED so the
// recursion's per-lane E gather is one contiguous b64:
//   rho (emission row) -> state s = (4*(rho>>6)+(rho&3))*16 + ((rho>>2)&15)
// Base frags (sum_d log1p(-p)*log2e) as bf16 hi+lo in k-slots 0/1.
// Zeroes partials.  ws: [0,32K) W frags, [32K,48K) base frags,
// [48K,56K) partials, [56K,64K) perm
// ---------------------------------------------------------------------------
__global__ void fhmm_init(const float* __restrict__ py,
                          unsigned short* __restrict__ ws16,
                          float* __restrict__ partials)
{
  const float LOG2E = 1.4426950408889634f;
  int t = blockIdx.x * 256 + threadIdx.x;
  if (t < 2048) partials[t] = 0.f;
  if (t < 2048) {
    int st = t >> 7, kk = (t >> 6) & 1, l = t & 63;
    int rho = st * 16 + (l & 15);
    int s = (4 * (rho >> 6) + (rho & 3)) * 16 + ((rho >> 2) & 15);
    int d0 = kk * 32 + 8 * (l >> 4);
    unsigned short* dst = ws16 + (size_t)t * 8;
#pragma unroll
    for (int i = 0; i < 8; ++i) {
      float p = py[s * 64 + d0 + i];
      dst[i] = bf16rn((logf(p) - log1pf(-p)) * LOG2E);
    }
  } else if (t < 3072) {
    int t2 = t - 2048;
    int st = t2 >> 6, l = t2 & 63;
    unsigned short v[8] = {0, 0, 0, 0, 0, 0, 0, 0};
    if (l < 16) {
      int rho = st * 16 + l;
      int s = (4 * (rho >> 6) + (rho & 3)) * 16 + ((rho >> 2) & 15);
      float base = 0.f;
      for (int d = 0; d < 64; ++d) base += log1pf(-py[s * 64 + d]);
      base *= LOG2E;
      unsigned short hi = bf16rn(base);
      float basehi = __uint_as_float(((unsigned)hi) << 16);
      v[0] = hi;
      v[1] = bf16rn(base - basehi);
    }
    unsigned short* dst = ws16 + (size_t)(2048 + t2) * 8;
#pragma unroll
    for (int i = 0; i < 8; ++i) dst[i] = v[i];
  }
}

// ---------------------------------------------------------------------------
// Fast counting sort by DESCENDING length: LDS histogram (atomics) +
// parallel Hillis-Steele scan + atomic within-bin ranks.  ~10 us.
// (Atomic ordering varies across replays; any valid permutation yields
//  bit-identical partials since each seq's L is deterministic and written
//  to partials[b].)
// ---------------------------------------------------------------------------
__global__ void fhmm_sort(const int* __restrict__ lengths, int* __restrict__ perm)
{
  __shared__ int hist[512];
  __shared__ int cnt[512];
  __shared__ int sa[512], sb2[512];
  const int tid = threadIdx.x;
  hist[tid] = 0; hist[tid + 256] = 0;
  cnt[tid] = 0;  cnt[tid + 256] = 0;
  __syncthreads();
  int myb[8];
#pragma unroll
  for (int u = 0; u < 8; ++u) {
    int i = tid + 256 * u;
    myb[u] = 512 - lengths[i];
    atomicAdd(&hist[myb[u]], 1);
  }
  __syncthreads();
  sa[tid] = hist[tid]; sa[tid + 256] = hist[tid + 256];
  __syncthreads();
  int* src = sa; int* dst = sb2;
  for (int off = 1; off < 512; off <<= 1) {
    for (int k = tid; k < 512; k += 256)
      dst[k] = src[k] + ((k >= off) ? src[k - off] : 0);
    __syncthreads();
    int* tp = src; src = dst; dst = tp;
  }
#pragma unroll
  for (int u = 0; u < 8; ++u) {
    int i = tid + 256 * u;
    int b2 = myb[u];
    int pos = src[b2] - hist[b2] + atomicAdd(&cnt[b2], 1);
    perm[pos] = i;
  }
}

// ---------------------------------------------------------------------------
// Main: one wave per sequence; recursion fully in registers via the MFMA
// free-transpose chain.  Per-step wave-uniform normalizer computed on the
// MFMA pipe (two ones-B MFMAs -> grand total in every reg), applied via rcp
// and accounted via off-chain log2 -- exact telescope for ANY wave-uniform
// scalar.  No LDS-based reduce in the loop-carried chain.
// ---------------------------------------------------------------------------
__global__ __launch_bounds__(256, 2) void fhmm_fwd2(
    const int* __restrict__ seq, const int* __restrict__ lengths,
    const float* __restrict__ pw, const float* __restrict__ px,
    const void* __restrict__ wfrag, const int* __restrict__ perm,
    float* __restrict__ partials)
{
  __shared__ uint2 e_lds[4][1024];   // 8KB per wave, wave-private (no barriers)

  const int tid = threadIdx.x;
  const int wv = tid >> 6, j = tid & 63;
  const int q = j >> 4, tl = j & 15;
  // CU-pairing remap: blocks (k, 511-k) land on the same CU under round-robin
  // dispatch -> complementary lengths (LPT), balanced per-SIMD issue work.
  const int bid = blockIdx.x;
  const int lb  = (bid < 256) ? bid : (767 - bid);
  const int b = perm[(lb << 2) | wv];
  if (b < 0 || b >= NB) return;
  uint2* e_w = e_lds[wv];
  const s16x8* wf_g = (const s16x8*)wfrag;
  const s16x8* w2_g = wf_g + 2048;

  // Tw/Tx zero-padded B-frags: b[i<4] = T[4q+i][tl], b[4..7] = 0
  s16x8 twb8, txb8;
  {
    frag8 a, c;
    a.u[0] = pack2(pw[(4 * q + 0) * 16 + tl], pw[(4 * q + 1) * 16 + tl]);
    a.u[1] = pack2(pw[(4 * q + 2) * 16 + tl], pw[(4 * q + 3) * 16 + tl]);
    a.u[2] = 0u; a.u[3] = 0u;
    c.u[0] = pack2(px[(4 * q + 0) * 16 + tl], px[(4 * q + 1) * 16 + tl]);
    c.u[1] = pack2(px[(4 * q + 2) * 16 + tl], px[(4 * q + 3) * 16 + tl]);
    c.u[2] = 0u; c.u[3] = 0u;
    twb8 = a.s8; txb8 = c.s8;
  }

  s16x8 f2 = {0, 0, 0, 0, 0, 0, 0, 0};   // ones in k-rows 0,1 (base column)
  if (q == 0) { f2[0] = (short)0x3F80; f2[1] = (short)0x3F80; }

  s16x8 ones8;                            // all-ones B (sum collapser)
  {
    frag8 o;
    o.u[0] = 0x3F803F80u; o.u[1] = 0x3F803F80u;
    o.u[2] = 0x3F803F80u; o.u[3] = 0x3F803F80u;
    ones8 = o.s8;
  }

  f32x4 p = {0.f, 0.f, 0.f, 0.f};        // V in D-layout; alpha0 = delta(0,0)
  if (j == 0) p[0] = 1.f;

  const int len = lengths[b];
  const int* ybase = seq + (size_t)b * NT * ND;

  int4 ya0, ya1, yb0, yb1;
  {
    const int* yr = ybase + (size_t)tl * ND + 8 * q;
    const int4* pp  = (const int4*)yr;
    const int4* pp2 = (const int4*)(yr + 32);
    ya0 = pp[0]; ya1 = pp[1]; yb0 = pp2[0]; yb1 = pp2[1];
  }

  float L2 = 0.f, Ls = 0.f;
  const f32x4 z4 = {0.f, 0.f, 0.f, 0.f};

  for (int t0 = 0; t0 < len; t0 += 16) {
    union { s16x8 s; unsigned u[4]; } f0u, f1u;
    f0u.u[0] = (ya0.x ? 0x3F80u : 0u) | (ya0.y ? 0x3F800000u : 0u);
    f0u.u[1] = (ya0.z ? 0x3F80u : 0u) | (ya0.w ? 0x3F800000u : 0u);
    f0u.u[2] = (ya1.x ? 0x3F80u : 0u) | (ya1.y ? 0x3F800000u : 0u);
    f0u.u[3] = (ya1.z ? 0x3F80u : 0u) | (ya1.w ? 0x3F800000u : 0u);
    f1u.u[0] = (yb0.x ? 0x3F80u : 0u) | (yb0.y ? 0x3F800000u : 0u);
    f1u.u[1] = (yb0.z ? 0x3F80u : 0u) | (yb0.w ? 0x3F800000u : 0u);
    f1u.u[2] = (yb1.x ? 0x3F80u : 0u) | (yb1.y ? 0x3F800000u : 0u);
    f1u.u[3] = (yb1.z ? 0x3F80u : 0u) | (yb1.w ? 0x3F800000u : 0u);
    const s16x8 f0 = f0u.s, f1 = f1u.s;

    if (t0 + 16 < len) {   // prefetch next chunk's y under compute
      const int* yr = ybase + (size_t)(t0 + 16 + tl) * ND + 8 * q;
      const int4* pp  = (const int4*)yr;
      const int4* pp2 = (const int4*)(yr + 32);
      ya0 = pp[0]; ya1 = pp[1]; yb0 = pp2[0]; yb1 = pp2[1];
    }

    // ---- emission: E_perm[rho][tl] (log2 units, incl base), bf16 to LDS ----
    float mloc = -3.0e38f;
#pragma unroll
    for (int st = 0; st < 16; ++st) {
      f32x4 acc = MFMA32(w2_g[st * 64 + j], f2, z4);
      acc = MFMA32(wf_g[(2 * st + 0) * 64 + j], f0, acc);
      acc = MFMA32(wf_g[(2 * st + 1) * 64 + j], f1, acc);
      mloc = fmaxf(mloc, fmaxf(fmaxf(acc[0], acc[1]), fmaxf(acc[2], acc[3])));
      unsigned lo = pack2(acc[0], acc[1]);
      unsigned hi = pack2(acc[2], acc[3]);
      e_w[tl * 64 + ((st * 4 + q) ^ tl)] = make_uint2(lo, hi);
    }
    mloc = cross_max1632(mloc);   // lane tl holds m_t for timestep t0+tl

    // ---- recursion: register-only; sum via ones-MFMA (no LDS reduce) ----
    const int nsteps = (len - t0 < 16) ? (len - t0) : 16;
    uint2 ev = e_w[j];            // it=0 slot
    for (int it = 0; it < nsteps; ++it) {
      const uint2 ec = ev;
      const int itn = (it + 1) & 15;
      ev = e_w[itn * 64 + (j ^ itn)];          // prefetch next step
      const float mm = __shfl(mloc, it);
      s16x8 vb = pack8t(p);                    // D-of-prev reused as A = V^T
      f32x4 P  = MFMA32(vb, twb8, z4);         // P  = V^T * Tw
      f32x4 S1 = MFMA32(vb, ones8, z4);        // row sums (col-uniform)
      s16x8 pb = pack8t(P);
      s16x8 sb = pack8t(S1);
      f32x4 U  = MFMA32(pb, txb8, z4);         // U  = Tw^T V Tx
      f32x4 S2 = MFMA32(sb, ones8, z4);        // grand total, all regs/lanes
      const float s   = fmaxf(S2[0], 1e-30f);  // wave-uniform normalizer
      const float inv = RCPF(s);
      Ls += LOG2F(s);                          // account EXACTLY what we apply
      L2 += mm;
      const float e0 = __uint_as_float(ec.x << 16);
      const float e1 = __uint_as_float(ec.x & 0xFFFF0000u);
      const float e2 = __uint_as_float(ec.y << 16);
      const float e3 = __uint_as_float(ec.y & 0xFFFF0000u);
      f32x4 pn;
      pn[0] = U[0] * EXP2F(e0 - mm) * inv;
      pn[1] = U[1] * EXP2F(e1 - mm) * inv;
      pn[2] = U[2] * EXP2F(e2 - mm) * inv;
      pn[3] = U[3] * EXP2F(e3 - mm) * inv;
      p = pn;
    }
  }
  // final total of p (ones-MFMA; <=0.4% rel err -> ~0.006 nats, negligible)
  {
    s16x8 vbf = pack8t(p);
    f32x4 F1 = MFMA32(vbf, ones8, z4);
    f32x4 F2 = MFMA32(pack8t(F1), ones8, z4);
    float sf = fmaxf(F2[0], 1e-35f);
    float L = (L2 + Ls + LOG2F(sf)) * 0.6931471805599453f;
    if (j == 0) partials[b] = L;
  }
}

// ---------------------------------------------------------------------------
// Round-1 fallback (block per sequence) for small workspace.
// ---------------------------------------------------------------------------
__global__ __launch_bounds__(256, 3) void fhmm_fwd1(
    const int* __restrict__ seq, const int* __restrict__ lengths,
    const float* __restrict__ pw, const float* __restrict__ px,
    const float* __restrict__ py, float* __restrict__ partials,
    float* __restrict__ out)
{
  const int b = blockIdx.x, tid = threadIdx.x;
  const int wp = tid >> 4, xc = tid & 15;
  float Twc[16], Txc[16], W[64], base = 0.f;
#pragma unroll
  for (int w = 0; w < 16; ++w) Twc[w] = pw[w * 16 + wp];
#pragma unroll
  for (int x = 0; x < 16; ++x) Txc[x] = px[x * 16 + xc];
#pragma unroll
  for (int d = 0; d < 64; ++d) {
    float pv = py[tid * 64 + d];
    W[d] = logf(pv) - log1pf(-pv);
    base += log1pf(-pv);
  }
  __shared__ __align__(16) float yf[64];
  __shared__ __align__(16) float v_s[256];
  __shared__ __align__(16) float tmp_s[256];
  __shared__ float red[8];
  const int len = lengths[b];
  const int* yb = seq + (size_t)b * (NT * ND);
  v_s[tid] = (tid == 0) ? 1.f : 0.f;
  float L = 0.f, ynext = 0.f;
  if (tid < 64) ynext = (float)yb[tid];
  for (int t = 0; t < len; ++t) {
    if (tid < 64) yf[tid] = ynext;
    __syncthreads();
    if (tid < 64 && (t + 1) < len) ynext = (float)yb[(t + 1) * ND + tid];
    float e0 = base, e1 = 0.f, e2 = 0.f, e3 = 0.f;
    const float4* y4p = (const float4*)yf;
#pragma unroll
    for (int i = 0; i < 16; ++i) {
      float4 y4 = y4p[i];
      e0 = fmaf(y4.x, W[4 * i + 0], e0); e1 = fmaf(y4.y, W[4 * i + 1], e1);
      e2 = fmaf(y4.z, W[4 * i + 2], e2); e3 = fmaf(y4.w, W[4 * i + 3], e3);
    }
    float e = (e0 + e1) + (e2 + e3);
    float s1a = 0.f, s1b = 0.f;
#pragma unroll
    for (int w = 0; w < 16; w += 2) {
      s1a = fmaf(Twc[w], v_s[w * 16 + xc], s1a);
      s1b = fmaf(Twc[w + 1], v_s[(w + 1) * 16 + xc], s1b);
    }
    tmp_s[tid] = s1a + s1b;
    float mm = e;
#pragma unroll
    for (int off = 32; off; off >>= 1) mm = fmaxf(mm, __shfl_xor(mm, off));
    if ((tid & 63) == 0) red[tid >> 6] = mm;
    __syncthreads();
    mm = fmaxf(fmaxf(red[0], red[1]), fmaxf(red[2], red[3]));
    float q0 = 0.f, q1 = 0.f;
    const float4* t4p = (const float4*)(tmp_s + wp * 16);
#pragma unroll
    for (int i = 0; i < 4; ++i) {
      float4 t4 = t4p[i];
      q0 = fmaf(t4.x, Txc[4 * i + 0], q0); q1 = fmaf(t4.y, Txc[4 * i + 1], q1);
      q0 = fmaf(t4.z, Txc[4 * i + 2], q0); q1 = fmaf(t4.w, Txc[4 * i + 3], q1);
    }
    float val = (q0 + q1) * __expf(e - mm);
    float s = val;
#pragma unroll
    for (int off = 32; off; off >>= 1) s += __shfl_xor(s, off);
    if ((tid & 63) == 0) red[4 + (tid >> 6)] = s;
    __syncthreads();
    s = (red[4] + red[5]) + (red[6] + red[7]);
    L += __logf(s) + mm;
    v_s[tid] = val * (1.0f / s);
  }
  if (partials) { if (tid == 0) partials[b] = L; }
  else { if (tid == 0) atomicAdd(out, L); }
}

// ---------------------------------------------------------------------------
// Finalize: deterministic tree-sum of per-sequence LLs + priors.
// ---------------------------------------------------------------------------
__global__ void fhmm_finalize(const float* __restrict__ partials,
                              const float* __restrict__ pw,
                              const float* __restrict__ px,
                              const float* __restrict__ py,
                              float* __restrict__ out)
{
  const int tid = threadIdx.x;
  float a = 0.f;
  if (partials) {
#pragma unroll
    for (int i = 0; i < 8; ++i) a += partials[tid + 256 * i];
  }
  {
    int i = tid >> 4, j = tid & 15;
    if (i != j) a += -0.9f * (logf(pw[tid]) + logf(px[tid]));
  }
  for (int k = 0; k < 64; ++k) {
    float p = py[tid * 64 + k];
    a += -0.9f * logf(p) - 0.1f * log1pf(-p);
  }
  __shared__ float red[256];
  red[tid] = a;
  __syncthreads();
  for (int s = 128; s > 0; s >>= 1) {
    if (tid < s) red[tid] += red[tid + s];
    __syncthreads();
  }
  if (tid == 0) {
    const float cst =
        2.f * (16.f * 0.2846828704729192f - 240.f * 2.2527126517342055f)
        - (2.2527126517342055f + 0.0663762397347443f) * 16384.f;
    out[0] = red[0] + cst;
  }
}

extern "C" void kernel_launch(void* const* d_in, const int* in_sizes, int n_in,
                              void* d_out, int out_size, void* d_ws, size_t ws_size,
                              hipStream_t stream) {
  const int*   seq = (const int*)d_in[0];
  const int*   len = (const int*)d_in[1];
  const float* pw  = (const float*)d_in[2];
  const float* px  = (const float*)d_in[3];
  const float* py  = (const float*)d_in[4];
  float*       out = (float*)d_out;

  const size_t NEED = 65536;  // 32K wfrag + 16K base + 8K partials + 8K perm
  if (ws_size >= NEED) {
    unsigned short* wf = (unsigned short*)d_ws;
    float* partials = (float*)((char*)d_ws + 49152);
    int*   perm     = (int*)((char*)d_ws + 57344);
    fhmm_init<<<12, 256, 0, stream>>>(py, wf, partials);
    fhmm_sort<<<1, 256, 0, stream>>>(len, perm);
    fhmm_fwd2<<<512, 256, 0, stream>>>(seq, len, pw, px, (const void*)wf, perm, partials);
    fhmm_finalize<<<1, 256, 0, stream>>>(partials, pw, px, py, out);
  } else if (ws_size >= 2048 * sizeof(float)) {
    float* partials = (float*)d_ws;
    fhmm_fwd1<<<NB, 256, 0, stream>>>(seq, len, pw, px, py, partials, out);
    fhmm_finalize<<<1, 256, 0, stream>>>(partials, pw, px, py, out);
  } else {
    fhmm_finalize<<<1, 256, 0, stream>>>(nullptr, pw, px, py, out);
    fhmm_fwd1<<<NB, 256, 0, stream>>>(seq, len, pw, px, py, nullptr, out);
  }
}

// Round 8
// 206.836 us; speedup vs baseline: 7.4905x; 1.2606x over previous
//
#include <hip/hip_runtime.h>
#include <math.h>

#define NB 2048
#define NT 512
#define ND 64

typedef float    f32x4 __attribute__((ext_vector_type(4)));
typedef short    s16x8 __attribute__((ext_vector_type(8)));

#define MFMA32(A,B,C) __builtin_amdgcn_mfma_f32_16x16x32_bf16((A),(B),(C),0,0,0)

#if __has_builtin(__builtin_amdgcn_exp2f)
#define EXP2F(x) __builtin_amdgcn_exp2f(x)
#else
#define EXP2F(x) __expf((x) * 0.6931471805599453f)
#endif
#if __has_builtin(__builtin_amdgcn_logf)
#define LOG2F(x) __builtin_amdgcn_logf(x)
#else
#define LOG2F(x) (__logf(x) * 1.4426950408889634f)
#endif
#if __has_builtin(__builtin_amdgcn_rcpf)
#define RCPF(x) __builtin_amdgcn_rcpf(x)
#else
#define RCPF(x) __fdividef(1.0f, (x))
#endif

// Pure-C bf16 round-to-nearest-even (validated) -- init-time only.
__device__ __forceinline__ unsigned short bf16rn(float f) {
  unsigned u = __float_as_uint(f);
  unsigned r = u + 0x7FFFu + ((u >> 16) & 1u);
  return (unsigned short)(r >> 16);
}
__device__ __forceinline__ unsigned pack2(float a, float b) {
  return (unsigned)bf16rn(a) | ((unsigned)bf16rn(b) << 16);
}
// Truncating bf16 pack (hot loop): 3 ops; uniform-scale bias cancels through
// the normalization accounting.
__device__ __forceinline__ unsigned pack2t(float a, float b) {
  return (__float_as_uint(a) >> 16) | (__float_as_uint(b) & 0xFFFF0000u);
}

union frag8 { s16x8 s8; unsigned u[4]; };

// pack D-layout f32x4 into a zero-padded MFMA32 A-frag (k = 8*(lane>>4)+i).
__device__ __forceinline__ s16x8 pack8t(f32x4 x) {
  frag8 r;
  r.u[0] = pack2t(x[0], x[1]);
  r.u[1] = pack2t(x[2], x[3]);
  r.u[2] = 0u; r.u[3] = 0u;
  return r.s8;
}

// ---------------------------------------------------------------------------
// Init: bf16 A-frags of W2 = logit(probs_y)*log2(e), rows PERMUTED so the
// recursion's per-lane gather is one contiguous access:
//   rho (emission row) -> state s = (4*(rho>>6)+(rho&3))*16 + ((rho>>2)&15)
// Base frags (sum_d log1p(-p)*log2e) as bf16 hi+lo in k-slots 0/1.
// Zeroes partials.  ws: [0,32K) W frags, [32K,48K) base frags,
// [48K,56K) partials, [56K,64K) perm
// ---------------------------------------------------------------------------
__global__ void fhmm_init(const float* __restrict__ py,
                          unsigned short* __restrict__ ws16,
                          float* __restrict__ partials)
{
  const float LOG2E = 1.4426950408889634f;
  int t = blockIdx.x * 256 + threadIdx.x;
  if (t < 2048) partials[t] = 0.f;
  if (t < 2048) {
    int st = t >> 7, kk = (t >> 6) & 1, l = t & 63;
    int rho = st * 16 + (l & 15);
    int s = (4 * (rho >> 6) + (rho & 3)) * 16 + ((rho >> 2) & 15);
    int d0 = kk * 32 + 8 * (l >> 4);
    unsigned short* dst = ws16 + (size_t)t * 8;
#pragma unroll
    for (int i = 0; i < 8; ++i) {
      float p = py[s * 64 + d0 + i];
      dst[i] = bf16rn((logf(p) - log1pf(-p)) * LOG2E);
    }
  } else if (t < 3072) {
    int t2 = t - 2048;
    int st = t2 >> 6, l = t2 & 63;
    unsigned short v[8] = {0, 0, 0, 0, 0, 0, 0, 0};
    if (l < 16) {
      int rho = st * 16 + l;
      int s = (4 * (rho >> 6) + (rho & 3)) * 16 + ((rho >> 2) & 15);
      float base = 0.f;
      for (int d = 0; d < 64; ++d) base += log1pf(-py[s * 64 + d]);
      base *= LOG2E;
      unsigned short hi = bf16rn(base);
      float basehi = __uint_as_float(((unsigned)hi) << 16);
      v[0] = hi;
      v[1] = bf16rn(base - basehi);
    }
    unsigned short* dst = ws16 + (size_t)(2048 + t2) * 8;
#pragma unroll
    for (int i = 0; i < 8; ++i) dst[i] = v[i];
  }
}

// ---------------------------------------------------------------------------
// Fast counting sort by DESCENDING length (LPT balance), parallel scan.
// ---------------------------------------------------------------------------
__global__ void fhmm_sort(const int* __restrict__ lengths, int* __restrict__ perm)
{
  __shared__ int hist[512];
  __shared__ int cnt[512];
  __shared__ int sa[512], sb2[512];
  const int tid = threadIdx.x;
  hist[tid] = 0; hist[tid + 256] = 0;
  cnt[tid] = 0;  cnt[tid + 256] = 0;
  __syncthreads();
  int myb[8];
#pragma unroll
  for (int u = 0; u < 8; ++u) {
    int i = tid + 256 * u;
    myb[u] = 512 - lengths[i];
    atomicAdd(&hist[myb[u]], 1);
  }
  __syncthreads();
  sa[tid] = hist[tid]; sa[tid + 256] = hist[tid + 256];
  __syncthreads();
  int* src = sa; int* dst = sb2;
  for (int off = 1; off < 512; off <<= 1) {
    for (int k = tid; k < 512; k += 256)
      dst[k] = src[k] + ((k >= off) ? src[k - off] : 0);
    __syncthreads();
    int* tp = src; src = dst; dst = tp;
  }
#pragma unroll
  for (int u = 0; u < 8; ++u) {
    int i = tid + 256 * u;
    int b2 = myb[u];
    int pos = src[b2] - hist[b2] + atomicAdd(&cnt[b2], 1);
    perm[pos] = i;
  }
}

// ---------------------------------------------------------------------------
// Main: one wave per sequence; recursion fully in registers via the MFMA
// free-transpose chain.  Emission now stores G = exp2(E - R) as f32
// (R = per-chunk running scale from realized log2-sum feedback), so the
// recursion has NO exp2, NO unpacking, NO cross-lane ops:
//   per step: 1 ds_read_b128 + pack8t + 4 MFMAs + rcp/log2 + 8 mults.
// Normalizer is the lagged mass (ones-MFMA), accounted exactly via Ls.
// LDS 64KB/block -> 2 blocks/CU -> 4 waves/SIMD resident.
// ---------------------------------------------------------------------------
__global__ __launch_bounds__(256, 2) void fhmm_fwd2(
    const int* __restrict__ seq, const int* __restrict__ lengths,
    const float* __restrict__ pw, const float* __restrict__ px,
    const void* __restrict__ wfrag, const int* __restrict__ perm,
    float* __restrict__ partials)
{
  __shared__ f32x4 e_lds[4][1024];   // 16KB per wave: [16 steps][64 slots] f32x4

  const int tid = threadIdx.x;
  const int wv = tid >> 6, j = tid & 63;
  const int q = j >> 4, tl = j & 15;
  // CU-pairing remap: complementary lengths on co-resident blocks (LPT).
  const int bid = blockIdx.x;
  const int lb  = (bid < 256) ? bid : (767 - bid);
  const int b = perm[(lb << 2) | wv];
  if (b < 0 || b >= NB) return;
  f32x4* e_w = e_lds[wv];
  const s16x8* wf_g = (const s16x8*)wfrag;
  const s16x8* w2_g = wf_g + 2048;

  // Tw/Tx zero-padded B-frags: b[i<4] = T[4q+i][tl], b[4..7] = 0
  s16x8 twb8, txb8;
  {
    frag8 a, c;
    a.u[0] = pack2(pw[(4 * q + 0) * 16 + tl], pw[(4 * q + 1) * 16 + tl]);
    a.u[1] = pack2(pw[(4 * q + 2) * 16 + tl], pw[(4 * q + 3) * 16 + tl]);
    a.u[2] = 0u; a.u[3] = 0u;
    c.u[0] = pack2(px[(4 * q + 0) * 16 + tl], px[(4 * q + 1) * 16 + tl]);
    c.u[1] = pack2(px[(4 * q + 2) * 16 + tl], px[(4 * q + 3) * 16 + tl]);
    c.u[2] = 0u; c.u[3] = 0u;
    twb8 = a.s8; txb8 = c.s8;
  }

  s16x8 f2 = {0, 0, 0, 0, 0, 0, 0, 0};   // ones in k-rows 0,1 (base column)
  if (q == 0) { f2[0] = (short)0x3F80; f2[1] = (short)0x3F80; }

  s16x8 ones8;                            // all-ones B (sum collapser)
  {
    frag8 o;
    o.u[0] = 0x3F803F80u; o.u[1] = 0x3F803F80u;
    o.u[2] = 0x3F803F80u; o.u[3] = 0x3F803F80u;
    ones8 = o.s8;
  }

  f32x4 p = {0.f, 0.f, 0.f, 0.f};        // V in D-layout; alpha0 = delta(0,0)
  if (j == 0) p[0] = 1.f;

  const int len = lengths[b];
  const int* ybase = seq + (size_t)b * NT * ND;

  int4 ya0, ya1, yb0, yb1;
  {
    const int* yr = ybase + (size_t)tl * ND + 8 * q;
    const int4* pp  = (const int4*)yr;
    const int4* pp2 = (const int4*)(yr + 32);
    ya0 = pp[0]; ya1 = pp[1]; yb0 = pp2[0]; yb1 = pp2[1];
  }

  float L2 = 0.f, Ls = 0.f, R = 0.f;
  const f32x4 z4 = {0.f, 0.f, 0.f, 0.f};

  for (int t0 = 0; t0 < len; t0 += 16) {
    union { s16x8 s; unsigned u[4]; } f0u, f1u;
    f0u.u[0] = (ya0.x ? 0x3F80u : 0u) | (ya0.y ? 0x3F800000u : 0u);
    f0u.u[1] = (ya0.z ? 0x3F80u : 0u) | (ya0.w ? 0x3F800000u : 0u);
    f0u.u[2] = (ya1.x ? 0x3F80u : 0u) | (ya1.y ? 0x3F800000u : 0u);
    f0u.u[3] = (ya1.z ? 0x3F80u : 0u) | (ya1.w ? 0x3F800000u : 0u);
    f1u.u[0] = (yb0.x ? 0x3F80u : 0u) | (yb0.y ? 0x3F800000u : 0u);
    f1u.u[1] = (yb0.z ? 0x3F80u : 0u) | (yb0.w ? 0x3F800000u : 0u);
    f1u.u[2] = (yb1.x ? 0x3F80u : 0u) | (yb1.y ? 0x3F800000u : 0u);
    f1u.u[3] = (yb1.z ? 0x3F80u : 0u) | (yb1.w ? 0x3F800000u : 0u);
    const s16x8 f0 = f0u.s, f1 = f1u.s;

    if (t0 + 16 < len) {   // prefetch next chunk's y under compute
      const int* yr = ybase + (size_t)(t0 + 16 + tl) * ND + 8 * q;
      const int4* pp  = (const int4*)yr;
      const int4* pp2 = (const int4*)(yr + 32);
      ya0 = pp[0]; ya1 = pp[1]; yb0 = pp2[0]; yb1 = pp2[1];
    }

    // ---- emission: G = exp2(E - R) as f32, one ds_write_b128 per st ----
#pragma unroll
    for (int st = 0; st < 16; ++st) {
      f32x4 acc = MFMA32(w2_g[st * 64 + j], f2, z4);
      acc = MFMA32(wf_g[(2 * st + 0) * 64 + j], f0, acc);
      acc = MFMA32(wf_g[(2 * st + 1) * 64 + j], f1, acc);
      f32x4 G;
      G[0] = EXP2F(fminf(acc[0] - R, 80.f));   // clamp = insurance vs R drift
      G[1] = EXP2F(fminf(acc[1] - R, 80.f));
      G[2] = EXP2F(fminf(acc[2] - R, 80.f));
      G[3] = EXP2F(fminf(acc[3] - R, 80.f));
      e_w[tl * 64 + ((st * 4 + q) ^ tl)] = G;
    }

    // ---- recursion: register-only MFMA chain; no exp2/unpack/cross-lane ----
    const int nsteps = (len - t0 < 16) ? (len - t0) : 16;
    float LsC = 0.f;
    f32x4 gv = e_w[j];            // it=0 slot (j ^ 0 = j)
    for (int it = 0; it < nsteps; ++it) {
      const f32x4 g = gv;
      const int itn = (it + 1) & 15;
      gv = e_w[itn * 64 + (j ^ itn)];          // prefetch next step
      s16x8 vb = pack8t(p);                    // D-of-prev reused as A = V^T
      f32x4 P  = MFMA32(vb, twb8, z4);         // P  = V^T * Tw
      f32x4 S1 = MFMA32(vb, ones8, z4);        // row sums
      f32x4 U  = MFMA32(pack8t(P), txb8, z4);  // U  = Tw^T V Tx
      f32x4 S2 = MFMA32(pack8t(S1), ones8, z4);// grand total (mass of p_prev)
      const float s   = fmaxf(S2[0], 1e-30f);
      const float inv = RCPF(s);
      LsC += LOG2F(s);
      f32x4 pn;
      pn[0] = (U[0] * inv) * g[0];             // U*inv <= O(1); * G bounded
      pn[1] = (U[1] * inv) * g[1];
      pn[2] = (U[2] * inv) * g[2];
      pn[3] = (U[3] * inv) * g[3];
      p = pn;
    }
    L2 += (float)nsteps * R;                    // applied shift accounting
    Ls += LsC;
    R  += LsC * 0.0625f;                        // track typical emission scale
  }
  // final total of p via ones-MFMA
  {
    f32x4 F1 = MFMA32(pack8t(p), ones8, z4);
    f32x4 F2 = MFMA32(pack8t(F1), ones8, z4);
    float sf = fmaxf(F2[0], 1e-35f);
    float L = (L2 + Ls + LOG2F(sf)) * 0.6931471805599453f;
    if (j == 0) partials[b] = L;
  }
}

// ---------------------------------------------------------------------------
// Round-1 fallback (block per sequence) for small workspace.
// ---------------------------------------------------------------------------
__global__ __launch_bounds__(256, 3) void fhmm_fwd1(
    const int* __restrict__ seq, const int* __restrict__ lengths,
    const float* __restrict__ pw, const float* __restrict__ px,
    const float* __restrict__ py, float* __restrict__ partials,
    float* __restrict__ out)
{
  const int b = blockIdx.x, tid = threadIdx.x;
  const int wp = tid >> 4, xc = tid & 15;
  float Twc[16], Txc[16], W[64], base = 0.f;
#pragma unroll
  for (int w = 0; w < 16; ++w) Twc[w] = pw[w * 16 + wp];
#pragma unroll
  for (int x = 0; x < 16; ++x) Txc[x] = px[x * 16 + xc];
#pragma unroll
  for (int d = 0; d < 64; ++d) {
    float pv = py[tid * 64 + d];
    W[d] = logf(pv) - log1pf(-pv);
    base += log1pf(-pv);
  }
  __shared__ __align__(16) float yf[64];
  __shared__ __align__(16) float v_s[256];
  __shared__ __align__(16) float tmp_s[256];
  __shared__ float red[8];
  const int len = lengths[b];
  const int* yb = seq + (size_t)b * (NT * ND);
  v_s[tid] = (tid == 0) ? 1.f : 0.f;
  float L = 0.f, ynext = 0.f;
  if (tid < 64) ynext = (float)yb[tid];
  for (int t = 0; t < len; ++t) {
    if (tid < 64) yf[tid] = ynext;
    __syncthreads();
    if (tid < 64 && (t + 1) < len) ynext = (float)yb[(t + 1) * ND + tid];
    float e0 = base, e1 = 0.f, e2 = 0.f, e3 = 0.f;
    const float4* y4p = (const float4*)yf;
#pragma unroll
    for (int i = 0; i < 16; ++i) {
      float4 y4 = y4p[i];
      e0 = fmaf(y4.x, W[4 * i + 0], e0); e1 = fmaf(y4.y, W[4 * i + 1], e1);
      e2 = fmaf(y4.z, W[4 * i + 2], e2); e3 = fmaf(y4.w, W[4 * i + 3], e3);
    }
    float e = (e0 + e1) + (e2 + e3);
    float s1a = 0.f, s1b = 0.f;
#pragma unroll
    for (int w = 0; w < 16; w += 2) {
      s1a = fmaf(Twc[w], v_s[w * 16 + xc], s1a);
      s1b = fmaf(Twc[w + 1], v_s[(w + 1) * 16 + xc], s1b);
    }
    tmp_s[tid] = s1a + s1b;
    float mm = e;
#pragma unroll
    for (int off = 32; off; off >>= 1) mm = fmaxf(mm, __shfl_xor(mm, off));
    if ((tid & 63) == 0) red[tid >> 6] = mm;
    __syncthreads();
    mm = fmaxf(fmaxf(red[0], red[1]), fmaxf(red[2], red[3]));
    float q0 = 0.f, q1 = 0.f;
    const float4* t4p = (const float4*)(tmp_s + wp * 16);
#pragma unroll
    for (int i = 0; i < 4; ++i) {
      float4 t4 = t4p[i];
      q0 = fmaf(t4.x, Txc[4 * i + 0], q0); q1 = fmaf(t4.y, Txc[4 * i + 1], q1);
      q0 = fmaf(t4.z, Txc[4 * i + 2], q0); q1 = fmaf(t4.w, Txc[4 * i + 3], q1);
    }
    float val = (q0 + q1) * __expf(e - mm);
    float s = val;
#pragma unroll
    for (int off = 32; off; off >>= 1) s += __shfl_xor(s, off);
    if ((tid & 63) == 0) red[4 + (tid >> 6)] = s;
    __syncthreads();
    s = (red[4] + red[5]) + (red[6] + red[7]);
    L += __logf(s) + mm;
    v_s[tid] = val * (1.0f / s);
  }
  if (partials) { if (tid == 0) partials[b] = L; }
  else { if (tid == 0) atomicAdd(out, L); }
}

// ---------------------------------------------------------------------------
// Finalize: deterministic tree-sum of per-sequence LLs + priors.
// ---------------------------------------------------------------------------
__global__ void fhmm_finalize(const float* __restrict__ partials,
                              const float* __restrict__ pw,
                              const float* __restrict__ px,
                              const float* __restrict__ py,
                              float* __restrict__ out)
{
  const int tid = threadIdx.x;
  float a = 0.f;
  if (partials) {
#pragma unroll
    for (int i = 0; i < 8; ++i) a += partials[tid + 256 * i];
  }
  {
    int i = tid >> 4, j = tid & 15;
    if (i != j) a += -0.9f * (logf(pw[tid]) + logf(px[tid]));
  }
  for (int k = 0; k < 64; ++k) {
    float p = py[tid * 64 + k];
    a += -0.9f * logf(p) - 0.1f * log1pf(-p);
  }
  __shared__ float red[256];
  red[tid] = a;
  __syncthreads();
  for (int s = 128; s > 0; s >>= 1) {
    if (tid < s) red[tid] += red[tid + s];
    __syncthreads();
  }
  if (tid == 0) {
    const float cst =
        2.f * (16.f * 0.2846828704729192f - 240.f * 2.2527126517342055f)
        - (2.2527126517342055f + 0.0663762397347443f) * 16384.f;
    out[0] = red[0] + cst;
  }
}

extern "C" void kernel_launch(void* const* d_in, const int* in_sizes, int n_in,
                              void* d_out, int out_size, void* d_ws, size_t ws_size,
                              hipStream_t stream) {
  const int*   seq = (const int*)d_in[0];
  const int*   len = (const int*)d_in[1];
  const float* pw  = (const float*)d_in[2];
  const float* px  = (const float*)d_in[3];
  const float* py  = (const float*)d_in[4];
  float*       out = (float*)d_out;

  const size_t NEED = 65536;  // 32K wfrag + 16K base + 8K partials + 8K perm
  if (ws_size >= NEED) {
    unsigned short* wf = (unsigned short*)d_ws;
    float* partials = (float*)((char*)d_ws + 49152);
    int*   perm     = (int*)((char*)d_ws + 57344);
    fhmm_init<<<12, 256, 0, stream>>>(py, wf, partials);
    fhmm_sort<<<1, 256, 0, stream>>>(len, perm);
    fhmm_fwd2<<<512, 256, 0, stream>>>(seq, len, pw, px, (const void*)wf, perm, partials);
    fhmm_finalize<<<1, 256, 0, stream>>>(partials, pw, px, py, out);
  } else if (ws_size >= 2048 * sizeof(float)) {
    float* partials = (float*)d_ws;
    fhmm_fwd1<<<NB, 256, 0, stream>>>(seq, len, pw, px, py, partials, out);
    fhmm_finalize<<<1, 256, 0, stream>>>(partials, pw, px, py, out);
  } else {
    fhmm_finalize<<<1, 256, 0, stream>>>(nullptr, pw, px, py, out);
    fhmm_fwd1<<<NB, 256, 0, stream>>>(seq, len, pw, px, py, nullptr, out);
  }
}